// Round 12
// baseline (241.000 us; speedup 1.0000x reference)
//
#include <hip/hip_runtime.h>
#include <stdint.h>

// ---- problem constants ----
#define BATCH 4
#define S_LEN 2048
#define D_DIM 1024
#define NH 16
#define HD 64
#define M_ROWS (BATCH * S_LEN)  // 8192
#define NQB (S_LEN / 128)       // 16 q-blocks
#define QSCALE 0.18033688011f   // 0.125 * log2(e): exp2-domain scores

using u16 = unsigned short;
typedef __attribute__((ext_vector_type(8))) __bf16 bf16x8;
typedef __attribute__((ext_vector_type(4))) float f32x4;
typedef __attribute__((ext_vector_type(16))) float f32x16;
typedef __attribute__((ext_vector_type(8))) unsigned short u16x8;

__device__ __forceinline__ float exp2fast(float x) { return __builtin_amdgcn_exp2f(x); }

__device__ __forceinline__ u16 f2bf(float f) {
  unsigned u = __builtin_bit_cast(unsigned, f);
  u += 0x7fffu + ((u >> 16) & 1u);  // RNE
  return (u16)(u >> 16);
}
// truncating pack: out = hi16(hi)<<16 | hi16(lo), one v_perm_b32.
// sel k<4 -> b.byte[k], k>=4 -> a.byte[k-4]; 0x07060302 -> {a3,a2,b3,b2}.
__device__ __forceinline__ unsigned pk2(float lo, float hi) {
  return __builtin_amdgcn_perm(__builtin_bit_cast(unsigned, hi),
                               __builtin_bit_cast(unsigned, lo), 0x07060302u);
}

// ---------------- fp32 -> bf16 conversions ----------------
__global__ void cvt_bf16_kernel(const float* __restrict__ in, u16* __restrict__ out, int n4) {
  int i = blockIdx.x * blockDim.x + threadIdx.x;
  if (i < n4) {
    float4 v = ((const float4*)in)[i];
    ushort4 o;
    o.x = f2bf(v.x); o.y = f2bf(v.y); o.z = f2bf(v.z); o.w = f2bf(v.w);
    ((ushort4*)out)[i] = o;
  }
}

__global__ void cvt_w_kernel(const float* __restrict__ W0, const float* __restrict__ W1,
                             const float* __restrict__ W2, const float* __restrict__ W3,
                             u16* __restrict__ out) {
  int y = blockIdx.y;
  const float* src = (y == 0) ? W0 : (y == 1) ? W1 : (y == 2) ? W2 : W3;
  u16* dst = out + (size_t)y * D_DIM * D_DIM;
  int i = blockIdx.x * blockDim.x + threadIdx.x;
  float4 v = ((const float4*)src)[i];
  ushort4 o;
  o.x = f2bf(v.x); o.y = f2bf(v.y); o.z = f2bf(v.z); o.w = f2bf(v.w);
  ((ushort4*)dst)[i] = o;
}

// ---------------- GEMM tile staging: 128x64 bf16 = 16KB = 1024 chunks ----------------
__device__ __forceinline__ void stage_tile(const u16* __restrict__ src, int srcK,
                                           u16* dst, int w, int lane) {
#pragma unroll
  for (int i = 0; i < 4; ++i) {
    int ic = w * 4 + i;
    int c = ic * 64 + lane;                 // 16B chunk index, 0..1023
    int row = c >> 3, g = c & 7, gs = g ^ (row & 7);
    __builtin_amdgcn_global_load_lds(
        (const __attribute__((address_space(1))) void*)(src + (size_t)row * srcK + gs * 8),
        (__attribute__((address_space(3))) void*)(dst + ic * 512), 16, 0, 0);
  }
}

// ---------------- fused QKV GEMM ----------------
__global__ __launch_bounds__(256)
void gemm_qkv_kernel(const u16* __restrict__ A, const u16* __restrict__ Bt,
                     const float* __restrict__ bq, const float* __restrict__ bk,
                     const float* __restrict__ bv,
                     u16* __restrict__ Qo, u16* __restrict__ Ko, u16* __restrict__ Vo) {
  __shared__ __align__(16) u16 As[128 * 64];
  __shared__ __align__(16) u16 Bs[128 * 64];
  const int tid = threadIdx.x;
  const int w = tid >> 6;
  const int lane = tid & 63;
  const int l15 = lane & 15, l4 = lane >> 4;
  const int m0 = blockIdx.y * 128, n0 = blockIdx.x * 128;
  const int wr = (w >> 1) * 64, wc = (w & 1) * 64;
  const int K = D_DIM;

  f32x4 acc[4][4] = {};

  for (int k0 = 0; k0 < K; k0 += 64) {
    __syncthreads();
    stage_tile(A + (size_t)m0 * K + k0, K, As, w, lane);
    stage_tile(Bt + (size_t)n0 * K + k0, K, Bs, w, lane);
    __syncthreads();

    bf16x8 a[4][2];
#pragma unroll
    for (int mb = 0; mb < 4; ++mb) {
#pragma unroll
      for (int ks = 0; ks < 2; ++ks) {
        int row = wr + mb * 16 + l15;
        int gsw = (ks * 4 + l4) ^ (row & 7);
        a[mb][ks] = *(const bf16x8*)(As + row * 64 + gsw * 8);
      }
    }
#pragma unroll
    for (int nb = 0; nb < 4; ++nb) {
      int row = wc + nb * 16 + l15;
      int g0 = (0 + l4) ^ (row & 7);
      int g1 = (4 + l4) ^ (row & 7);
      bf16x8 b0 = *(const bf16x8*)(Bs + row * 64 + g0 * 8);
      bf16x8 b1 = *(const bf16x8*)(Bs + row * 64 + g1 * 8);
#pragma unroll
      for (int mb = 0; mb < 4; ++mb) {
        acc[mb][nb] = __builtin_amdgcn_mfma_f32_16x16x32_bf16(a[mb][0], b0, acc[mb][nb], 0, 0, 0);
        acc[mb][nb] = __builtin_amdgcn_mfma_f32_16x16x32_bf16(a[mb][1], b1, acc[mb][nb], 0, 0, 0);
      }
    }
  }

  const int which = n0 >> 10;
  const float* bias = (which == 0) ? bq : (which == 1) ? bk : bv;
  u16* dst = (which == 0) ? Qo : (which == 1) ? Ko : Vo;
  const float scale = (which == 0) ? QSCALE : 1.0f;

#pragma unroll
  for (int mb = 0; mb < 4; ++mb) {
#pragma unroll
    for (int nb = 0; nb < 4; ++nb) {
#pragma unroll
      for (int r = 0; r < 4; ++r) {
        int m = m0 + wr + mb * 16 + l4 * 4 + r;
        int n = n0 + wc + nb * 16 + l15;
        int col = n & 1023;
        float v = (acc[mb][nb][r] + bias[col]) * scale;
        int bb = m >> 11;
        int ss = m & (S_LEN - 1);
        int hh = col >> 6;
        int hd = col & (HD - 1);
        dst[(((size_t)bb * NH + hh) * S_LEN + ss) * HD + hd] = f2bf(v);
      }
    }
  }
}

// ---------------- output projection GEMM (fp32 out) ----------------
__global__ __launch_bounds__(256)
void gemm_out_kernel(const u16* __restrict__ A, const u16* __restrict__ Bt,
                     const float* __restrict__ bias, float* __restrict__ Cout) {
  __shared__ __align__(16) u16 As[128 * 64];
  __shared__ __align__(16) u16 Bs[128 * 64];
  const int tid = threadIdx.x;
  const int w = tid >> 6;
  const int lane = tid & 63;
  const int l15 = lane & 15, l4 = lane >> 4;
  const int m0 = blockIdx.y * 128, n0 = blockIdx.x * 128;
  const int wr = (w >> 1) * 64, wc = (w & 1) * 64;
  const int K = D_DIM, N = D_DIM;

  f32x4 acc[4][4] = {};

  for (int k0 = 0; k0 < K; k0 += 64) {
    __syncthreads();
    stage_tile(A + (size_t)m0 * K + k0, K, As, w, lane);
    stage_tile(Bt + (size_t)n0 * K + k0, K, Bs, w, lane);
    __syncthreads();

    bf16x8 a[4][2];
#pragma unroll
    for (int mb = 0; mb < 4; ++mb) {
#pragma unroll
      for (int ks = 0; ks < 2; ++ks) {
        int row = wr + mb * 16 + l15;
        int gsw = (ks * 4 + l4) ^ (row & 7);
        a[mb][ks] = *(const bf16x8*)(As + row * 64 + gsw * 8);
      }
    }
#pragma unroll
    for (int nb = 0; nb < 4; ++nb) {
      int row = wc + nb * 16 + l15;
      int g0 = (0 + l4) ^ (row & 7);
      int g1 = (4 + l4) ^ (row & 7);
      bf16x8 b0 = *(const bf16x8*)(Bs + row * 64 + g0 * 8);
      bf16x8 b1 = *(const bf16x8*)(Bs + row * 64 + g1 * 8);
#pragma unroll
      for (int mb = 0; mb < 4; ++mb) {
        acc[mb][nb] = __builtin_amdgcn_mfma_f32_16x16x32_bf16(a[mb][0], b0, acc[mb][nb], 0, 0, 0);
        acc[mb][nb] = __builtin_amdgcn_mfma_f32_16x16x32_bf16(a[mb][1], b1, acc[mb][nb], 0, 0, 0);
      }
    }
  }

#pragma unroll
  for (int mb = 0; mb < 4; ++mb) {
#pragma unroll
    for (int nb = 0; nb < 4; ++nb) {
#pragma unroll
      for (int r = 0; r < 4; ++r) {
        int m = m0 + wr + mb * 16 + l4 * 4 + r;
        int n = n0 + wc + nb * 16 + l15;
        Cout[(size_t)m * N + n] = acc[mb][nb][r] + bias[n];
      }
    }
  }
}

// ---------------- causal flash attention ----------------
// KVBLK=128 staged per barrier pair (two 64-key halves, compute body per half).
// stage_k: 64x64 half-tile, t64 = index in 64-row units.
__device__ __forceinline__ void stage_k(const u16* __restrict__ Kg, size_t base, int t64,
                                        u16* Kd, int w, int lane) {
#pragma unroll
  for (int i = 0; i < 2; ++i) {
    int ic = w * 2 + i;
    int c = ic * 64 + lane;
    int row = c >> 3, g = c & 7, gs = g ^ (row & 7);
    __builtin_amdgcn_global_load_lds(
        (const __attribute__((address_space(1))) void*)(Kg + base + (size_t)(t64 * 64 + row) * HD + gs * 8),
        (__attribute__((address_space(3))) void*)(Kd + ic * 512), 16, 0, 0);
  }
}

// build two A-frags (keys 0..15 and 16..31 of a 32-key half) from st
__device__ __forceinline__ void pfrag(const f32x16& st, int hi, bf16x8& fa, bf16x8& fb) {
  unsigned c0 = pk2(st[0], st[1]),   c1 = pk2(st[2], st[3]);
  unsigned c2 = pk2(st[4], st[5]),   c3 = pk2(st[6], st[7]);
  unsigned c4 = pk2(st[8], st[9]),   c5 = pk2(st[10], st[11]);
  unsigned c6 = pk2(st[12], st[13]), c7 = pk2(st[14], st[15]);
  unsigned p0 = __shfl_xor(c0, 32), p1 = __shfl_xor(c1, 32);
  unsigned p2 = __shfl_xor(c2, 32), p3 = __shfl_xor(c3, 32);
  unsigned p4 = __shfl_xor(c4, 32), p5 = __shfl_xor(c5, 32);
  unsigned p6 = __shfl_xor(c6, 32), p7 = __shfl_xor(c7, 32);
  union { unsigned u[4]; bf16x8 v; } a, b;
  a.u[0] = hi ? p2 : c0; a.u[1] = hi ? p3 : c1;
  a.u[2] = hi ? c2 : p0; a.u[3] = hi ? c3 : p1;
  b.u[0] = hi ? p6 : c4; b.u[1] = hi ? p7 : c5;
  b.u[2] = hi ? c6 : p4; b.u[3] = hi ? c7 : p5;
  fa = a.v; fb = b.v;
}

__global__ __launch_bounds__(256)
void attn_kernel(const u16* __restrict__ Q, const u16* __restrict__ Kg,
                 const u16* __restrict__ Vg, u16* __restrict__ ctx) {
  __shared__ __align__(16) u16 Ks[2][2][64 * 64];  // [buf][half] K double buffer
  __shared__ __align__(16) u16 Vt[2][64 * 64];     // [half] V^T [d][key], swizzled

  const int tid = threadIdx.x;
  const int w = tid >> 6, lane = tid & 63;
  const int l31 = lane & 31, hi = lane >> 5;
  const int hi4 = hi * 4, hi8 = hi * 8;
  const int bh = blockIdx.y;
  const size_t base = (size_t)bh * S_LEN * HD;
  const int b = bh >> 4, h = bh & (NH - 1);

  const int vkey = tid & 63;
  const int vd0 = (tid >> 6) * 16;

#pragma unroll 1
  for (int seg = 0; seg < 2; ++seg) {
    const int qb = seg ? (NQB - 1 - blockIdx.x) : blockIdx.x;
    const int Qw = qb * 128 + w * 32;
    const int q_g = Qw + l31;

    bf16x8 qf[4];
#pragma unroll
    for (int step = 0; step < 4; ++step)
      qf[step] = *(const bf16x8*)(Q + base + (size_t)q_g * HD + step * 16 + hi8);

    f32x16 oacc0 = {}, oacc1 = {};
    float mrun = -1e30f, lrun = 0.f;

    const int nkt2 = qb + 1;   // 128-key tiles

    stage_k(Kg, base, 0, Ks[0][0], w, lane);
    stage_k(Kg, base, 1, Ks[0][1], w, lane);
    u16x8 va0, va1, vb0, vb1;
    {
      const u16* gva = Vg + base + (size_t)vkey * HD + vd0;
      const u16* gvb = Vg + base + (size_t)(64 + vkey) * HD + vd0;
      va0 = *(const u16x8*)gva; va1 = *(const u16x8*)(gva + 8);
      vb0 = *(const u16x8*)gvb; vb1 = *(const u16x8*)(gvb + 8);
    }

    for (int kt2 = 0; kt2 < nkt2; ++kt2) {
      const int cur = kt2 & 1;
      const bool more = (kt2 + 1 < nkt2);

      // V(kt2) regs -> Vt halves (transpose), granule XOR by (d>>2)&7
#pragma unroll
      for (int j = 0; j < 8; ++j) {
        int d0 = vd0 + j, d1 = vd0 + 8 + j;
        int s0 = (((vkey >> 3) ^ ((d0 >> 2) & 7)) << 3) + (vkey & 7);
        int s1 = (((vkey >> 3) ^ ((d1 >> 2) & 7)) << 3) + (vkey & 7);
        Vt[0][d0 * 64 + s0] = va0[j];
        Vt[0][d1 * 64 + s1] = va1[j];
        Vt[1][d0 * 64 + s0] = vb0[j];
        Vt[1][d1 * 64 + s1] = vb1[j];
      }
      __syncthreads();   // Vt + Ks[cur] ready (vmcnt drained at barrier)

      if (more) {
        stage_k(Kg, base, 2 * (kt2 + 1), Ks[cur ^ 1][0], w, lane);
        stage_k(Kg, base, 2 * (kt2 + 1) + 1, Ks[cur ^ 1][1], w, lane);
        const u16* gva = Vg + base + (size_t)((kt2 + 1) * 128 + vkey) * HD + vd0;
        const u16* gvb = Vg + base + (size_t)((kt2 + 1) * 128 + 64 + vkey) * HD + vd0;
        va0 = *(const u16x8*)gva; va1 = *(const u16x8*)(gva + 8);
        vb0 = *(const u16x8*)gvb; vb1 = *(const u16x8*)(gvb + 8);
      }

#pragma unroll
      for (int hh2 = 0; hh2 < 2; ++hh2) {
        const int kb64 = kt2 * 128 + hh2 * 64;
        if (kb64 > Qw + 31) continue;
        const u16* Kb = &Ks[cur][hh2][0];
        const u16* Vb = &Vt[hh2][0];

        // ---- swapped QK^T: st[key][q] (log2-domain) ----
        f32x16 st0 = {}, st1 = {};
#pragma unroll
        for (int step = 0; step < 4; ++step) {
          int r0 = l31, r1 = 32 + l31;
          bf16x8 kf0 = *(const bf16x8*)(Kb + r0 * 64 + (((step * 2 + hi) ^ (r0 & 7)) << 3));
          bf16x8 kf1 = *(const bf16x8*)(Kb + r1 * 64 + (((step * 2 + hi) ^ (r1 & 7)) << 3));
          st0 = __builtin_amdgcn_mfma_f32_32x32x16_bf16(kf0, qf[step], st0, 0, 0, 0);
          st1 = __builtin_amdgcn_mfma_f32_32x32x16_bf16(kf1, qf[step], st1, 0, 0, 0);
        }

        // ---- causal mask ----
        if (kb64 + 63 > Qw) {
#pragma unroll
          for (int r = 0; r < 16; ++r) {
            int key0 = kb64 + hi4 + (r & 3) + 8 * (r >> 2);
            if (key0 > q_g) st0[r] = -1e30f;
            if (key0 + 32 > q_g) st1[r] = -1e30f;
          }
        }

        // ---- in-register softmax, tree reductions ----
        float mt[16];
#pragma unroll
        for (int r = 0; r < 16; ++r) mt[r] = fmaxf(st0[r], st1[r]);
#pragma unroll
        for (int s = 8; s >= 1; s >>= 1)
#pragma unroll
          for (int r = 0; r < 8; ++r)
            if (r < s) mt[r] = fmaxf(mt[r], mt[r + s]);
        float tm = fmaxf(mt[0], __shfl_xor(mt[0], 32));

        if (__any(tm > mrun)) {          // exact defer-rescale
          float mnew = fmaxf(mrun, tm);
          float rs = exp2fast(mrun - mnew);
          mrun = mnew;
          lrun *= rs;
#pragma unroll
          for (int r = 0; r < 16; ++r) {
            float rsb = __shfl(rs, (r & 3) + 8 * (r >> 2) + hi4);
            oacc0[r] *= rsb;
            oacc1[r] *= rsb;
          }
        }

        float sa[16];
#pragma unroll
        for (int r = 0; r < 16; ++r) {
          st0[r] = exp2fast(st0[r] - mrun);
          st1[r] = exp2fast(st1[r] - mrun);
          sa[r] = st0[r] + st1[r];
        }
#pragma unroll
        for (int s = 8; s >= 1; s >>= 1)
#pragma unroll
          for (int r = 0; r < 8; ++r)
            if (r < s) sa[r] += sa[r + s];
        lrun += sa[0] + __shfl_xor(sa[0], 32);

        // ---- P -> bf16 A-frags ----
        bf16x8 paf0, paf1, paf2, paf3;
        pfrag(st0, hi, paf0, paf1);
        pfrag(st1, hi, paf2, paf3);

        // ---- PV ----
#pragma unroll
        for (int ks = 0; ks < 4; ++ks) {
          bf16x8 pa = (ks == 0) ? paf0 : (ks == 1) ? paf1 : (ks == 2) ? paf2 : paf3;
          int d0 = l31;
          bf16x8 vf0 = *(const bf16x8*)(Vb + d0 * 64 + (((ks * 2 + hi) ^ ((d0 >> 2) & 7)) << 3));
          int d1 = 32 + l31;
          bf16x8 vf1 = *(const bf16x8*)(Vb + d1 * 64 + (((ks * 2 + hi) ^ ((d1 >> 2) & 7)) << 3));
          oacc0 = __builtin_amdgcn_mfma_f32_32x32x16_bf16(pa, vf0, oacc0, 0, 0, 0);
          oacc1 = __builtin_amdgcn_mfma_f32_32x32x16_bf16(pa, vf1, oacc1, 0, 0, 0);
        }
      }
      __syncthreads();   // all waves done with Ks[cur]/Vt before next writes
    }

    // ---- epilogue ----
#pragma unroll
    for (int r = 0; r < 16; ++r) {
      float lr = __shfl(lrun, (r & 3) + 8 * (r >> 2) + hi4);
      float inv = 1.0f / lr;
      int srow = Qw + (r & 3) + 8 * (r >> 2) + hi4;
      size_t rowbase = ((size_t)b * S_LEN + srow) * D_DIM + h * HD;
      ctx[rowbase + l31] = f2bf(oacc0[r] * inv);
      ctx[rowbase + 32 + l31] = f2bf(oacc1[r] * inv);
    }
  }
}

// ---------------- host launcher ----------------
extern "C" void kernel_launch(void* const* d_in, const int* in_sizes, int n_in,
                              void* d_out, int out_size, void* d_ws, size_t ws_size,
                              hipStream_t stream) {
  const float* x  = (const float*)d_in[0];
  const float* Wq = (const float*)d_in[1];
  const float* bq = (const float*)d_in[2];
  const float* Wk = (const float*)d_in[3];
  const float* bk = (const float*)d_in[4];
  const float* Wv = (const float*)d_in[5];
  const float* bv = (const float*)d_in[6];
  const float* Wo = (const float*)d_in[7];
  const float* bo = (const float*)d_in[8];

  char* ws = (char*)d_ws;
  const size_t MB = 1024 * 1024;
  u16* xb     = (u16*)(ws + 0);        // 16 MB [8192,1024] bf16
  u16* Wqkvb  = (u16*)(ws + 16 * MB);  // 6 MB  [3072,1024] bf16 (Wq|Wk|Wv rows)
  u16* Wob    = (u16*)(ws + 22 * MB);  // 2 MB
  u16* Qb     = (u16*)(ws + 24 * MB);  // 16 MB [B,H,S,HD]
  u16* Kb     = (u16*)(ws + 40 * MB);
  u16* Vb     = (u16*)(ws + 56 * MB);
  u16* ctxb   = xb;                    // reuse xb after QKV GEMM

  cvt_bf16_kernel<<<(M_ROWS * D_DIM / 4 + 255) / 256, 256, 0, stream>>>(x, xb, M_ROWS * D_DIM / 4);
  cvt_w_kernel<<<dim3(D_DIM * D_DIM / 4 / 256, 4), 256, 0, stream>>>(Wq, Wk, Wv, Wo, Wqkvb);

  gemm_qkv_kernel<<<dim3(3 * D_DIM / 128, M_ROWS / 128), 256, 0, stream>>>(
      xb, Wqkvb, bq, bk, bv, Qb, Kb, Vb);

  attn_kernel<<<dim3(NQB / 2, BATCH * NH), 256, 0, stream>>>(Qb, Kb, Vb, ctxb);

  gemm_out_kernel<<<dim3(D_DIM / 128, M_ROWS / 128), 256, 0, stream>>>(
      ctxb, Wob, bo, (float*)d_out);
}

// Round 13
// 196.053 us; speedup vs baseline: 1.2293x; 1.2293x over previous
//
#include <hip/hip_runtime.h>
#include <stdint.h>

// ---- problem constants ----
#define BATCH 4
#define S_LEN 2048
#define D_DIM 1024
#define NH 16
#define HD 64
#define M_ROWS (BATCH * S_LEN)  // 8192
#define NQB (S_LEN / 128)       // 16 q-blocks
#define QSCALE 0.18033688011f   // 0.125 * log2(e): exp2-domain scores

using u16 = unsigned short;
typedef __attribute__((ext_vector_type(8))) __bf16 bf16x8;
typedef __attribute__((ext_vector_type(4))) float f32x4;
typedef __attribute__((ext_vector_type(16))) float f32x16;
typedef __attribute__((ext_vector_type(8))) unsigned short u16x8;

__device__ __forceinline__ float exp2fast(float x) { return __builtin_amdgcn_exp2f(x); }

__device__ __forceinline__ u16 f2bf(float f) {
  unsigned u = __builtin_bit_cast(unsigned, f);
  u += 0x7fffu + ((u >> 16) & 1u);  // RNE
  return (u16)(u >> 16);
}
// truncating pack: out = hi16(hi)<<16 | hi16(lo), one v_perm_b32. [proven r12]
__device__ __forceinline__ unsigned pk2(float lo, float hi) {
  return __builtin_amdgcn_perm(__builtin_bit_cast(unsigned, hi),
                               __builtin_bit_cast(unsigned, lo), 0x07060302u);
}

// ---------------- fp32 -> bf16 conversions ----------------
__global__ void cvt_bf16_kernel(const float* __restrict__ in, u16* __restrict__ out, int n4) {
  int i = blockIdx.x * blockDim.x + threadIdx.x;
  if (i < n4) {
    float4 v = ((const float4*)in)[i];
    ushort4 o;
    o.x = f2bf(v.x); o.y = f2bf(v.y); o.z = f2bf(v.z); o.w = f2bf(v.w);
    ((ushort4*)out)[i] = o;
  }
}

__global__ void cvt_w_kernel(const float* __restrict__ W0, const float* __restrict__ W1,
                             const float* __restrict__ W2, const float* __restrict__ W3,
                             u16* __restrict__ out) {
  int y = blockIdx.y;
  const float* src = (y == 0) ? W0 : (y == 1) ? W1 : (y == 2) ? W2 : W3;
  u16* dst = out + (size_t)y * D_DIM * D_DIM;
  int i = blockIdx.x * blockDim.x + threadIdx.x;
  float4 v = ((const float4*)src)[i];
  ushort4 o;
  o.x = f2bf(v.x); o.y = f2bf(v.y); o.z = f2bf(v.z); o.w = f2bf(v.w);
  ((ushort4*)dst)[i] = o;
}

// ---------------- GEMM tile staging: 128x64 bf16 = 16KB = 1024 chunks ----------------
__device__ __forceinline__ void stage_tile(const u16* __restrict__ src, int srcK,
                                           u16* dst, int w, int lane) {
#pragma unroll
  for (int i = 0; i < 4; ++i) {
    int ic = w * 4 + i;
    int c = ic * 64 + lane;                 // 16B chunk index, 0..1023
    int row = c >> 3, g = c & 7, gs = g ^ (row & 7);
    __builtin_amdgcn_global_load_lds(
        (const __attribute__((address_space(1))) void*)(src + (size_t)row * srcK + gs * 8),
        (__attribute__((address_space(3))) void*)(dst + ic * 512), 16, 0, 0);
  }
}

// ---------------- fused QKV GEMM ----------------
__global__ __launch_bounds__(256)
void gemm_qkv_kernel(const u16* __restrict__ A, const u16* __restrict__ Bt,
                     const float* __restrict__ bq, const float* __restrict__ bk,
                     const float* __restrict__ bv,
                     u16* __restrict__ Qo, u16* __restrict__ Ko, u16* __restrict__ Vo) {
  __shared__ __align__(16) u16 As[128 * 64];
  __shared__ __align__(16) u16 Bs[128 * 64];
  const int tid = threadIdx.x;
  const int w = tid >> 6;
  const int lane = tid & 63;
  const int l15 = lane & 15, l4 = lane >> 4;
  const int m0 = blockIdx.y * 128, n0 = blockIdx.x * 128;
  const int wr = (w >> 1) * 64, wc = (w & 1) * 64;
  const int K = D_DIM;

  f32x4 acc[4][4] = {};

  for (int k0 = 0; k0 < K; k0 += 64) {
    __syncthreads();
    stage_tile(A + (size_t)m0 * K + k0, K, As, w, lane);
    stage_tile(Bt + (size_t)n0 * K + k0, K, Bs, w, lane);
    __syncthreads();

    bf16x8 a[4][2];
#pragma unroll
    for (int mb = 0; mb < 4; ++mb) {
#pragma unroll
      for (int ks = 0; ks < 2; ++ks) {
        int row = wr + mb * 16 + l15;
        int gsw = (ks * 4 + l4) ^ (row & 7);
        a[mb][ks] = *(const bf16x8*)(As + row * 64 + gsw * 8);
      }
    }
#pragma unroll
    for (int nb = 0; nb < 4; ++nb) {
      int row = wc + nb * 16 + l15;
      int g0 = (0 + l4) ^ (row & 7);
      int g1 = (4 + l4) ^ (row & 7);
      bf16x8 b0 = *(const bf16x8*)(Bs + row * 64 + g0 * 8);
      bf16x8 b1 = *(const bf16x8*)(Bs + row * 64 + g1 * 8);
#pragma unroll
      for (int mb = 0; mb < 4; ++mb) {
        acc[mb][nb] = __builtin_amdgcn_mfma_f32_16x16x32_bf16(a[mb][0], b0, acc[mb][nb], 0, 0, 0);
        acc[mb][nb] = __builtin_amdgcn_mfma_f32_16x16x32_bf16(a[mb][1], b1, acc[mb][nb], 0, 0, 0);
      }
    }
  }

  const int which = n0 >> 10;
  const float* bias = (which == 0) ? bq : (which == 1) ? bk : bv;
  u16* dst = (which == 0) ? Qo : (which == 1) ? Ko : Vo;
  const float scale = (which == 0) ? QSCALE : 1.0f;

#pragma unroll
  for (int mb = 0; mb < 4; ++mb) {
#pragma unroll
    for (int nb = 0; nb < 4; ++nb) {
#pragma unroll
      for (int r = 0; r < 4; ++r) {
        int m = m0 + wr + mb * 16 + l4 * 4 + r;
        int n = n0 + wc + nb * 16 + l15;
        int col = n & 1023;
        float v = (acc[mb][nb][r] + bias[col]) * scale;
        int bb = m >> 11;
        int ss = m & (S_LEN - 1);
        int hh = col >> 6;
        int hd = col & (HD - 1);
        dst[(((size_t)bb * NH + hh) * S_LEN + ss) * HD + hd] = f2bf(v);
      }
    }
  }
}

// ---------------- output projection GEMM (fp32 out) ----------------
__global__ __launch_bounds__(256)
void gemm_out_kernel(const u16* __restrict__ A, const u16* __restrict__ Bt,
                     const float* __restrict__ bias, float* __restrict__ Cout) {
  __shared__ __align__(16) u16 As[128 * 64];
  __shared__ __align__(16) u16 Bs[128 * 64];
  const int tid = threadIdx.x;
  const int w = tid >> 6;
  const int lane = tid & 63;
  const int l15 = lane & 15, l4 = lane >> 4;
  const int m0 = blockIdx.y * 128, n0 = blockIdx.x * 128;
  const int wr = (w >> 1) * 64, wc = (w & 1) * 64;
  const int K = D_DIM, N = D_DIM;

  f32x4 acc[4][4] = {};

  for (int k0 = 0; k0 < K; k0 += 64) {
    __syncthreads();
    stage_tile(A + (size_t)m0 * K + k0, K, As, w, lane);
    stage_tile(Bt + (size_t)n0 * K + k0, K, Bs, w, lane);
    __syncthreads();

    bf16x8 a[4][2];
#pragma unroll
    for (int mb = 0; mb < 4; ++mb) {
#pragma unroll
      for (int ks = 0; ks < 2; ++ks) {
        int row = wr + mb * 16 + l15;
        int gsw = (ks * 4 + l4) ^ (row & 7);
        a[mb][ks] = *(const bf16x8*)(As + row * 64 + gsw * 8);
      }
    }
#pragma unroll
    for (int nb = 0; nb < 4; ++nb) {
      int row = wc + nb * 16 + l15;
      int g0 = (0 + l4) ^ (row & 7);
      int g1 = (4 + l4) ^ (row & 7);
      bf16x8 b0 = *(const bf16x8*)(Bs + row * 64 + g0 * 8);
      bf16x8 b1 = *(const bf16x8*)(Bs + row * 64 + g1 * 8);
#pragma unroll
      for (int mb = 0; mb < 4; ++mb) {
        acc[mb][nb] = __builtin_amdgcn_mfma_f32_16x16x32_bf16(a[mb][0], b0, acc[mb][nb], 0, 0, 0);
        acc[mb][nb] = __builtin_amdgcn_mfma_f32_16x16x32_bf16(a[mb][1], b1, acc[mb][nb], 0, 0, 0);
      }
    }
  }

#pragma unroll
  for (int mb = 0; mb < 4; ++mb) {
#pragma unroll
    for (int nb = 0; nb < 4; ++nb) {
#pragma unroll
      for (int r = 0; r < 4; ++r) {
        int m = m0 + wr + mb * 16 + l4 * 4 + r;
        int n = n0 + wc + nb * 16 + l15;
        Cout[(size_t)m * N + n] = acc[mb][nb][r] + bias[n];
      }
    }
  }
}

// ---------------- causal flash attention (r11 structure) ----------------
__device__ __forceinline__ void stage_k(const u16* __restrict__ Kg, size_t base, int kt,
                                        u16* Kd, int w, int lane) {
#pragma unroll
  for (int i = 0; i < 2; ++i) {
    int ic = w * 2 + i;
    int c = ic * 64 + lane;
    int row = c >> 3, g = c & 7, gs = g ^ (row & 7);
    __builtin_amdgcn_global_load_lds(
        (const __attribute__((address_space(1))) void*)(Kg + base + (size_t)(kt * 64 + row) * HD + gs * 8),
        (__attribute__((address_space(3))) void*)(Kd + ic * 512), 16, 0, 0);
  }
}

// build two A-frags (keys 0..15 and 16..31 of a 32-key half) from st
__device__ __forceinline__ void pfrag(const f32x16& st, int hi, bf16x8& fa, bf16x8& fb) {
  unsigned c0 = pk2(st[0], st[1]),   c1 = pk2(st[2], st[3]);
  unsigned c2 = pk2(st[4], st[5]),   c3 = pk2(st[6], st[7]);
  unsigned c4 = pk2(st[8], st[9]),   c5 = pk2(st[10], st[11]);
  unsigned c6 = pk2(st[12], st[13]), c7 = pk2(st[14], st[15]);
  unsigned p0 = __shfl_xor(c0, 32), p1 = __shfl_xor(c1, 32);
  unsigned p2 = __shfl_xor(c2, 32), p3 = __shfl_xor(c3, 32);
  unsigned p4 = __shfl_xor(c4, 32), p5 = __shfl_xor(c5, 32);
  unsigned p6 = __shfl_xor(c6, 32), p7 = __shfl_xor(c7, 32);
  union { unsigned u[4]; bf16x8 v; } a, b;
  a.u[0] = hi ? p2 : c0; a.u[1] = hi ? p3 : c1;
  a.u[2] = hi ? c2 : p0; a.u[3] = hi ? c3 : p1;
  b.u[0] = hi ? p6 : c4; b.u[1] = hi ? p7 : c5;
  b.u[2] = hi ? c6 : p4; b.u[3] = hi ? c7 : p5;
  fa = a.v; fb = b.v;
}

__global__ __launch_bounds__(256)
void attn_kernel(const u16* __restrict__ Q, const u16* __restrict__ Kg,
                 const u16* __restrict__ Vg, u16* __restrict__ ctx) {
  __shared__ __align__(16) u16 Ks[2][64 * 64];   // K double buffer
  __shared__ __align__(16) u16 Vt[64 * 64];      // V^T [d][key], granule-XOR swizzled

  const int tid = threadIdx.x;
  const int w = tid >> 6, lane = tid & 63;
  const int l31 = lane & 31, hi = lane >> 5;
  const int hi4 = hi * 4, hi8 = hi * 8;
  const int bh = blockIdx.y;
  const size_t base = (size_t)bh * S_LEN * HD;
  const int b = bh >> 4, h = bh & (NH - 1);

  const int vkey = tid & 63;
  const int vd0 = (tid >> 6) * 16;

#pragma unroll 1
  for (int seg = 0; seg < 2; ++seg) {
    const int qb = seg ? (NQB - 1 - blockIdx.x) : blockIdx.x;
    const int Qw = qb * 128 + w * 32;
    const int q_g = Qw + l31;

    bf16x8 qf[4];
#pragma unroll
    for (int step = 0; step < 4; ++step)
      qf[step] = *(const bf16x8*)(Q + base + (size_t)q_g * HD + step * 16 + hi8);

    f32x16 oacc0 = {}, oacc1 = {};
    float mrun = -1e30f, lrun = 0.f;

    const int nkt = 2 * qb + 2;

    stage_k(Kg, base, 0, Ks[0], w, lane);
    u16x8 vv0, vv1;
    {
      const u16* gv = Vg + base + (size_t)vkey * HD + vd0;
      vv0 = *(const u16x8*)gv;
      vv1 = *(const u16x8*)(gv + 8);
    }

    for (int kt = 0; kt < nkt; ++kt) {
      const int cur = kt & 1;
      const bool more = (kt + 1 < nkt);

      // V(kt) regs -> Vt (transpose), granule XOR by (d>>2)&7
#pragma unroll
      for (int j = 0; j < 8; ++j) {
        int d0 = vd0 + j;
        Vt[d0 * 64 + (((vkey >> 3) ^ ((d0 >> 2) & 7)) << 3) + (vkey & 7)] = vv0[j];
        int d1 = vd0 + 8 + j;
        Vt[d1 * 64 + (((vkey >> 3) ^ ((d1 >> 2) & 7)) << 3) + (vkey & 7)] = vv1[j];
      }
      __syncthreads();   // Vt + Ks[cur] ready

      if (more) {
        stage_k(Kg, base, kt + 1, Ks[cur ^ 1], w, lane);
        const u16* gv = Vg + base + (size_t)((kt + 1) * 64 + vkey) * HD + vd0;
        vv0 = *(const u16x8*)gv;
        vv1 = *(const u16x8*)(gv + 8);
      }

      const u16* Kb = &Ks[cur][0];

      if (kt * 64 <= Qw + 31) {
        // ---- swapped QK^T: st[key][q] (log2-domain) ----
        f32x16 st0 = {}, st1 = {};
#pragma unroll
        for (int step = 0; step < 4; ++step) {
          int r0 = l31, r1 = 32 + l31;
          bf16x8 kf0 = *(const bf16x8*)(Kb + r0 * 64 + (((step * 2 + hi) ^ (r0 & 7)) << 3));
          bf16x8 kf1 = *(const bf16x8*)(Kb + r1 * 64 + (((step * 2 + hi) ^ (r1 & 7)) << 3));
          st0 = __builtin_amdgcn_mfma_f32_32x32x16_bf16(kf0, qf[step], st0, 0, 0, 0);
          st1 = __builtin_amdgcn_mfma_f32_32x32x16_bf16(kf1, qf[step], st1, 0, 0, 0);
        }

        // ---- causal mask ----
        if (kt * 64 + 63 > Qw) {
#pragma unroll
          for (int r = 0; r < 16; ++r) {
            int key0 = kt * 64 + hi4 + (r & 3) + 8 * (r >> 2);
            if (key0 > q_g) st0[r] = -1e30f;
            if (key0 + 32 > q_g) st1[r] = -1e30f;
          }
        }

        // ---- in-register softmax, tree reductions [proven r12] ----
        float mt[16];
#pragma unroll
        for (int r = 0; r < 16; ++r) mt[r] = fmaxf(st0[r], st1[r]);
#pragma unroll
        for (int s = 8; s >= 1; s >>= 1)
#pragma unroll
          for (int r = 0; r < 8; ++r)
            if (r < s) mt[r] = fmaxf(mt[r], mt[r + s]);
        float tm = fmaxf(mt[0], __shfl_xor(mt[0], 32));

        if (__any(tm > mrun)) {          // exact defer-rescale
          float mnew = fmaxf(mrun, tm);
          float rs = exp2fast(mrun - mnew);
          mrun = mnew;
          lrun *= rs;
#pragma unroll
          for (int r = 0; r < 16; ++r) {
            float rsb = __shfl(rs, (r & 3) + 8 * (r >> 2) + hi4);
            oacc0[r] *= rsb;
            oacc1[r] *= rsb;
          }
        }

        float sa[16];
#pragma unroll
        for (int r = 0; r < 16; ++r) {
          st0[r] = exp2fast(st0[r] - mrun);
          st1[r] = exp2fast(st1[r] - mrun);
          sa[r] = st0[r] + st1[r];
        }
#pragma unroll
        for (int s = 8; s >= 1; s >>= 1)
#pragma unroll
          for (int r = 0; r < 8; ++r)
            if (r < s) sa[r] += sa[r + s];
        lrun += sa[0] + __shfl_xor(sa[0], 32);

        // ---- P -> bf16 A-frags ----
        bf16x8 paf0, paf1, paf2, paf3;
        pfrag(st0, hi, paf0, paf1);
        pfrag(st1, hi, paf2, paf3);

        // ---- PV ----
#pragma unroll
        for (int ks = 0; ks < 4; ++ks) {
          bf16x8 pa = (ks == 0) ? paf0 : (ks == 1) ? paf1 : (ks == 2) ? paf2 : paf3;
          int d0 = l31;
          bf16x8 vf0 = *(const bf16x8*)(Vt + d0 * 64 + (((ks * 2 + hi) ^ ((d0 >> 2) & 7)) << 3));
          int d1 = 32 + l31;
          bf16x8 vf1 = *(const bf16x8*)(Vt + d1 * 64 + (((ks * 2 + hi) ^ ((d1 >> 2) & 7)) << 3));
          oacc0 = __builtin_amdgcn_mfma_f32_32x32x16_bf16(pa, vf0, oacc0, 0, 0, 0);
          oacc1 = __builtin_amdgcn_mfma_f32_32x32x16_bf16(pa, vf1, oacc1, 0, 0, 0);
        }
      }
      __syncthreads();
    }

    // ---- epilogue ----
#pragma unroll
    for (int r = 0; r < 16; ++r) {
      float lr = __shfl(lrun, (r & 3) + 8 * (r >> 2) + hi4);
      float inv = 1.0f / lr;
      int srow = Qw + (r & 3) + 8 * (r >> 2) + hi4;
      size_t rowbase = ((size_t)b * S_LEN + srow) * D_DIM + h * HD;
      ctx[rowbase + l31] = f2bf(oacc0[r] * inv);
      ctx[rowbase + 32 + l31] = f2bf(oacc1[r] * inv);
    }
  }
}

// ---------------- host launcher ----------------
extern "C" void kernel_launch(void* const* d_in, const int* in_sizes, int n_in,
                              void* d_out, int out_size, void* d_ws, size_t ws_size,
                              hipStream_t stream) {
  const float* x  = (const float*)d_in[0];
  const float* Wq = (const float*)d_in[1];
  const float* bq = (const float*)d_in[2];
  const float* Wk = (const float*)d_in[3];
  const float* bk = (const float*)d_in[4];
  const float* Wv = (const float*)d_in[5];
  const float* bv = (const float*)d_in[6];
  const float* Wo = (const float*)d_in[7];
  const float* bo = (const float*)d_in[8];

  char* ws = (char*)d_ws;
  const size_t MB = 1024 * 1024;
  u16* xb     = (u16*)(ws + 0);        // 16 MB [8192,1024] bf16
  u16* Wqkvb  = (u16*)(ws + 16 * MB);  // 6 MB  [3072,1024] bf16 (Wq|Wk|Wv rows)
  u16* Wob    = (u16*)(ws + 22 * MB);  // 2 MB
  u16* Qb     = (u16*)(ws + 24 * MB);  // 16 MB [B,H,S,HD]
  u16* Kb     = (u16*)(ws + 40 * MB);
  u16* Vb     = (u16*)(ws + 56 * MB);
  u16* ctxb   = xb;                    // reuse xb after QKV GEMM

  cvt_bf16_kernel<<<(M_ROWS * D_DIM / 4 + 255) / 256, 256, 0, stream>>>(x, xb, M_ROWS * D_DIM / 4);
  cvt_w_kernel<<<dim3(D_DIM * D_DIM / 4 / 256, 4), 256, 0, stream>>>(Wq, Wk, Wv, Wo, Wqkvb);

  gemm_qkv_kernel<<<dim3(3 * D_DIM / 128, M_ROWS / 128), 256, 0, stream>>>(
      xb, Wqkvb, bq, bk, bv, Qb, Kb, Vb);

  attn_kernel<<<dim3(NQB / 2, BATCH * NH), 256, 0, stream>>>(Qb, Kb, Vb, ctxb);

  gemm_out_kernel<<<dim3(D_DIM / 128, M_ROWS / 128), 256, 0, stream>>>(
      ctxb, Wob, bo, (float*)d_out);
}